// Round 3
// baseline (122.396 us; speedup 1.0000x reference)
//
#include <hip/hip_runtime.h>
#include <hip/hip_bf16.h>

// ModConv2d: per-sample modulated 3x3 conv (N=8, C=64->64, 256x256) + MLPs.
// Kernel 1: MLPs -> w_bf[n][kidx][cb][cout][8ci] (bf16, A-frag-contiguous) + bias.
// Kernel 2: implicit-GEMM conv, mfma_f32_32x32x16_bf16 (2x FLOP/LDS-byte vs 16x16).
//   Block: 512 thr (8 waves), 1 sample x 4 output rows x 256 cols x 64 couts.
//   Wave (r,h): row h0+r, col half h. Per wave 2m x 4j 32x32 tiles, acc 128 VGPR.
//   Weights read per-step from global (L2-resident per XCD via n=bid&7 swizzle).
//   x LDS: [6 rows][258][16ci] bf16, 40B entry stride, double-buffered (123.8 KB).
//   One barrier per 16-ci chunk; staging split load-early/write-late (T14).

typedef short bf16x8 __attribute__((ext_vector_type(8)));
typedef float f32x16 __attribute__((ext_vector_type(16)));

#define NB 8
#define CIN 64
#define COUT 64
#define HH 256
#define WW 256
#define HWP (HH * WW)
#define AUXD 128
#define HIDD 256

#define XENT 40
#define XROW (258 * XENT)   // 10320
#define XBUF (6 * XROW)     // 61920
#define SMEMB (2 * XBUF)    // 123840

__device__ __forceinline__ unsigned short f2bf(float f) {
    unsigned u = __builtin_bit_cast(unsigned, f);
    u += 0x7FFFu + ((u >> 16) & 1u);   // RNE
    return (unsigned short)(u >> 16);
}

__device__ __forceinline__ unsigned pk2(float a, float b, float vm) {
    return (unsigned)f2bf(a * vm) | ((unsigned)f2bf(b * vm) << 16);
}

__device__ __forceinline__ void mfma32(f32x16& d, bf16x8 a, bf16x8 b) {
    asm volatile("v_mfma_f32_32x32x16_bf16 %0, %1, %2, %0"
                 : "+v"(d) : "v"(a), "v"(b));
}

// ---------------- Kernel 1: MLPs ----------------
__global__ __launch_bounds__(256) void mlp_kernel(
    const float* __restrict__ y, const float* __restrict__ weight,
    const float* __restrict__ fc_w1, const float* __restrict__ fc_b1,
    const float* __restrict__ fc_prelu,
    const float* __restrict__ fc_w2, const float* __restrict__ fc_b2,
    const float* __restrict__ bias_w1, const float* __restrict__ bias_b1,
    const float* __restrict__ bias_prelu,
    const float* __restrict__ bias_w2, const float* __restrict__ bias_b2,
    unsigned short* __restrict__ w_bf, float* __restrict__ bvec)
{
    const int n = blockIdx.y;
    const int c = blockIdx.x;
    const int tid = threadIdx.x;
    __shared__ float ylds[AUXD];
    __shared__ float hl[HIDD];
    if (tid < AUXD) ylds[tid] = y[n * AUXD + tid];
    __syncthreads();

    if (c < 16) {
        float s = fc_b1[tid];
        const float* wrow = fc_w1 + tid * AUXD;
        #pragma unroll 4
        for (int a = 0; a < AUXD; ++a) s += ylds[a] * wrow[a];
        float ap = fc_prelu[0];
        hl[tid] = s >= 0.f ? s : ap * s;
        __syncthreads();

        int o = c * 256 + tid;           // o = cout*64 + ci
        float t = fc_b2[o];
        const float* w2row = fc_w2 + o * HIDD;
        #pragma unroll 4
        for (int h = 0; h < HIDD; ++h) t += hl[h] * w2row[h];
        float mod = 1.f / (1.f + expf(-t));
        int cout = o >> 6, ci = o & 63;
        int cb = ci >> 3, cl = ci & 7;
        #pragma unroll
        for (int k = 0; k < 9; ++k) {
            float wv = weight[o * 9 + k];
            // unit (16B) = ((n*9+k)*8 + cb)*64 + cout; halfword cl
            w_bf[((((n * 9 + k) * 8 + cb) * 64 + cout) << 3) + cl] = f2bf(mod * wv);
        }
    } else {
        float s = bias_b1[tid];
        const float* wrow = bias_w1 + tid * AUXD;
        #pragma unroll 4
        for (int a = 0; a < AUXD; ++a) s += ylds[a] * wrow[a];
        float ap = bias_prelu[0];
        hl[tid] = s >= 0.f ? s : ap * s;
        __syncthreads();
        if (tid < COUT) {
            float t = bias_b2[tid];
            const float* w2row = bias_w2 + tid * HIDD;
            #pragma unroll 4
            for (int h = 0; h < HIDD; ++h) t += hl[h] * w2row[h];
            bvec[n * COUT + tid] = t;
        }
    }
}

// ---------------- Kernel 2: conv ----------------
#define ISSUE(k) { _Pragma("unroll") \
    for (int i = 0; i < 16; ++i) st[i] = xr[k][(size_t)(nci + i) * HWP]; }

#define WRITE(k) { float vm = vmr[k]; \
    unsigned char* dst = nx + (rg + 2 * (k)) * XROW + (sw + 1) * XENT; \
    uint4 lo, hi; \
    lo.x = pk2(st[0], st[1], vm);  lo.y = pk2(st[2], st[3], vm); \
    lo.z = pk2(st[4], st[5], vm);  lo.w = pk2(st[6], st[7], vm); \
    hi.x = pk2(st[8], st[9], vm);  hi.y = pk2(st[10], st[11], vm); \
    hi.z = pk2(st[12], st[13], vm); hi.w = pk2(st[14], st[15], vm); \
    *(uint4*)dst = lo; *(uint4*)(dst + 16) = hi; }

__global__ __launch_bounds__(512, 2) void conv_kernel(
    const float* __restrict__ x, const unsigned short* __restrict__ w_bf,
    const float* __restrict__ bvec, float* __restrict__ out)
{
    __shared__ __align__(16) unsigned char smem[SMEMB];

    const int bid = blockIdx.x;
    const int n = bid & 7;              // sample -> XCD (weights + x L2 locality)
    const int h0 = (bid >> 3) * 4;      // first output row

    const int tid = threadIdx.x;
    const int lane = tid & 63;
    const int wave = tid >> 6;
    const int wr = wave >> 1;           // output row 0..3
    const int wh = wave & 1;            // col half
    const int l5 = lane >> 5;           // K half
    const int l31 = lane & 31;

    const int sw = tid & 255;           // staging col
    const int rg = tid >> 8;            // staging row group: rows rg, rg+2, rg+4

    // staging row pointers (clamped + zero mask for image edges)
    const float* xr[3];
    float vmr[3];
    #pragma unroll
    for (int k = 0; k < 3; ++k) {
        int r = rg + 2 * k;
        int hin = h0 - 1 + r;
        bool val = (hin >= 0) && (hin < HH);
        xr[k] = x + (size_t)n * CIN * HWP + (size_t)(val ? hin : 0) * WW + sw;
        vmr[k] = val ? 1.f : 0.f;
    }

    const uint4* wsrc = (const uint4*)w_bf + (size_t)n * (9 * 8 * 64);

    // zero halo columns (entries 0 and 257, 6 rows, both buffers) — written once
    if (tid < 48) {
        int s = tid & 1, id = tid >> 1;
        int r = id % 6, rest = id / 6;          // rest 0..3
        int side = rest & 1, buf = rest >> 1;
        uint4 z; z.x = z.y = z.z = z.w = 0u;
        *(uint4*)(smem + buf * XBUF + r * XROW + (side ? 257 : 0) * XENT + s * 16) = z;
    }

    // prologue: stage chunk 0 (ci 0..15) into buf 0
    #pragma unroll
    for (int k = 0; k < 3; ++k) {
        float st[16];
        #pragma unroll
        for (int i = 0; i < 16; ++i) st[i] = xr[k][(size_t)i * HWP];
        float vm = vmr[k];
        unsigned char* dst = smem + (rg + 2 * k) * XROW + (sw + 1) * XENT;
        uint4 lo, hi;
        lo.x = pk2(st[0], st[1], vm);  lo.y = pk2(st[2], st[3], vm);
        lo.z = pk2(st[4], st[5], vm);  lo.w = pk2(st[6], st[7], vm);
        hi.x = pk2(st[8], st[9], vm);  hi.y = pk2(st[10], st[11], vm);
        hi.z = pk2(st[12], st[13], vm); hi.w = pk2(st[14], st[15], vm);
        *(uint4*)dst = lo; *(uint4*)(dst + 16) = hi;
    }

    // acc init = per-cout bias (D row = (reg&3) + 8*(reg>>2) + 4*l5)
    f32x16 acc[2][4];
    #pragma unroll
    for (int m = 0; m < 2; ++m) {
        #pragma unroll
        for (int reg = 0; reg < 16; ++reg)
            acc[m][0][reg] = bvec[n * COUT + m * 32 + (reg & 3) + 8 * (reg >> 2) + 4 * l5];
        #pragma unroll
        for (int j = 1; j < 4; ++j) acc[m][j] = acc[m][0];
    }

    __syncthreads();

    #pragma unroll
    for (int c = 0; c < 4; ++c) {
        const int p = c & 1;
        const unsigned char* rbuf = smem + p * XBUF;
        unsigned char* nx = smem + (p ^ 1) * XBUF;
        const bool more = (c < 3);
        const int nci = (c + 1) * 16;

        // A-frags for kidx 0 (global, L2-hot): lane l holds A[cout=m*32+l31][k=8*l5+j]
        bf16x8 aA, aB, nA, nB;
        {
            int u = (c * 2 + l5) * 64 + l31;
            aA = *(const bf16x8*)(wsrc + u);
            aB = *(const bf16x8*)(wsrc + u + 32);
        }

        float st[16];
        if (more) ISSUE(0);   // T14: issue next-chunk loads early

        #pragma unroll
        for (int kidx = 0; kidx < 9; ++kidx) {
            const int kh = kidx / 3, kw = kidx % 3;
            if (kidx < 8) {
                int u = ((kidx + 1) * 8 + c * 2 + l5) * 64 + l31;
                nA = *(const bf16x8*)(wsrc + u);
                nB = *(const bf16x8*)(wsrc + u + 32);
            }
            // B-frags: lane l holds B[k=8*l5+j][col=l31] = x[row wr+kh][col+kw]
            bf16x8 bfr[4];
            #pragma unroll
            for (int j = 0; j < 4; ++j)
                bfr[j] = *(const bf16x8*)(rbuf + (wr + kh) * XROW +
                          (wh * 128 + j * 32 + l31 + kw) * XENT + l5 * 16);

            if (more) {
                if (kidx == 3)      { WRITE(0); ISSUE(1); }
                else if (kidx == 6) { WRITE(1); ISSUE(2); }
                else if (kidx == 8) { WRITE(2); }
            }

            #pragma unroll
            for (int j = 0; j < 4; ++j) {
                mfma32(acc[0][j], aA, bfr[j]);
                mfma32(acc[1][j], aB, bfr[j]);
            }
            aA = nA; aB = nB;
        }
        __syncthreads();
    }

    // epilogue: D col = l31, row = (reg&3) + 8*(reg>>2) + 4*l5
    const int hout = h0 + wr;
    float* ob = out + ((size_t)n * COUT * HH + hout) * WW;
    #pragma unroll
    for (int m = 0; m < 2; ++m) {
        #pragma unroll
        for (int j = 0; j < 4; ++j) {
            int colb = wh * 128 + j * 32 + l31;
            #pragma unroll
            for (int reg = 0; reg < 16; ++reg) {
                int cout = m * 32 + (reg & 3) + 8 * (reg >> 2) + 4 * l5;
                ob[(size_t)cout * HWP + colb] = acc[m][j][reg];
            }
        }
    }
}

extern "C" void kernel_launch(void* const* d_in, const int* in_sizes, int n_in,
                              void* d_out, int out_size, void* d_ws, size_t ws_size,
                              hipStream_t stream) {
    const float* x          = (const float*)d_in[0];
    const float* y          = (const float*)d_in[1];
    const float* weight     = (const float*)d_in[2];
    const float* fc_w1      = (const float*)d_in[3];
    const float* fc_b1      = (const float*)d_in[4];
    const float* fc_prelu   = (const float*)d_in[5];
    const float* fc_w2      = (const float*)d_in[6];
    const float* fc_b2      = (const float*)d_in[7];
    const float* bias_w1    = (const float*)d_in[8];
    const float* bias_b1    = (const float*)d_in[9];
    const float* bias_prelu = (const float*)d_in[10];
    const float* bias_w2    = (const float*)d_in[11];
    const float* bias_b2    = (const float*)d_in[12];
    float* out = (float*)d_out;

    unsigned short* w_bf = (unsigned short*)d_ws;                       // 589824 B
    float* bvec = (float*)((char*)d_ws + (size_t)NB * 9 * 64 * 64 * 2); // 2048 B

    hipLaunchKernelGGL(mlp_kernel, dim3(17, 8), dim3(256), 0, stream,
                       y, weight, fc_w1, fc_b1, fc_prelu, fc_w2, fc_b2,
                       bias_w1, bias_b1, bias_prelu, bias_w2, bias_b2, w_bf, bvec);
    hipLaunchKernelGGL(conv_kernel, dim3(512), dim3(512), 0, stream,
                       x, w_bf, bvec, out);
}

// Round 4
// 120.185 us; speedup vs baseline: 1.0184x; 1.0184x over previous
//
#include <hip/hip_runtime.h>
#include <hip/hip_bf16.h>

// ModConv2d: per-sample modulated 3x3 conv (N=8, C=64->64, 256x256) + MLPs.
// Kernel 1: MLPs -> w_bf[n][kidx][cb][cout][8ci] (bf16, A-frag 16B units) + bias.
// Kernel 2: implicit-GEMM conv, mfma_f32_32x32x16_bf16.
//   Block: 512 thr (8 waves), 2 output rows x 256 cols x 64 couts. Grid 1024.
//   Wave (wr, wq): row h0+wr, cols wq*64..+63; acc[2m][2j] 32x32 tiles = 64 VGPR.
//   Weights from global (L2-resident per XCD, n = bid&7), 1-kidx reg prefetch.
//   x LDS: [4 rows][258 w][32B ci-entry], UNPADDED (32x32 B-read = contiguous
//   1024B/wave = conflict-free), double-buffered = 66 KB -> 2 blocks/CU,
//   VGPR<=128 -> 4 waves/SIMD (16 waves/CU). One barrier per 16-ci chunk.

typedef short bf16x8 __attribute__((ext_vector_type(8)));
typedef float f32x16 __attribute__((ext_vector_type(16)));

#define NB 8
#define CIN 64
#define COUT 64
#define HH 256
#define WW 256
#define HWP (HH * WW)
#define AUXD 128
#define HIDD 256

#define XROW (258 * 32)     // 8256 B per staged row
#define XBUF (4 * XROW)     // 33024 B per buffer
#define SMEMB (2 * XBUF)    // 66048 B

__device__ __forceinline__ unsigned short f2bf(float f) {
    unsigned u = __builtin_bit_cast(unsigned, f);
    u += 0x7FFFu + ((u >> 16) & 1u);   // RNE
    return (unsigned short)(u >> 16);
}

__device__ __forceinline__ unsigned pk2(float a, float b, float vm) {
    return (unsigned)f2bf(a * vm) | ((unsigned)f2bf(b * vm) << 16);
}

__device__ __forceinline__ void mfma32(f32x16& d, bf16x8 a, bf16x8 b) {
    asm volatile("v_mfma_f32_32x32x16_bf16 %0, %1, %2, %0"
                 : "+v"(d) : "v"(a), "v"(b));
}

// ---------------- Kernel 1: MLPs ----------------
__global__ __launch_bounds__(256) void mlp_kernel(
    const float* __restrict__ y, const float* __restrict__ weight,
    const float* __restrict__ fc_w1, const float* __restrict__ fc_b1,
    const float* __restrict__ fc_prelu,
    const float* __restrict__ fc_w2, const float* __restrict__ fc_b2,
    const float* __restrict__ bias_w1, const float* __restrict__ bias_b1,
    const float* __restrict__ bias_prelu,
    const float* __restrict__ bias_w2, const float* __restrict__ bias_b2,
    unsigned short* __restrict__ w_bf, float* __restrict__ bvec)
{
    const int n = blockIdx.y;
    const int c = blockIdx.x;
    const int tid = threadIdx.x;
    __shared__ float ylds[AUXD];
    __shared__ float hl[HIDD];
    if (tid < AUXD) ylds[tid] = y[n * AUXD + tid];
    __syncthreads();

    if (c < 16) {
        float s = fc_b1[tid];
        const float* wrow = fc_w1 + tid * AUXD;
        #pragma unroll 4
        for (int a = 0; a < AUXD; ++a) s += ylds[a] * wrow[a];
        float ap = fc_prelu[0];
        hl[tid] = s >= 0.f ? s : ap * s;
        __syncthreads();

        int o = c * 256 + tid;           // o = cout*64 + ci
        float t = fc_b2[o];
        const float* w2row = fc_w2 + o * HIDD;
        #pragma unroll 4
        for (int h = 0; h < HIDD; ++h) t += hl[h] * w2row[h];
        float mod = 1.f / (1.f + expf(-t));
        int cout = o >> 6, ci = o & 63;
        int cb = ci >> 3, cl = ci & 7;
        #pragma unroll
        for (int k = 0; k < 9; ++k) {
            float wv = weight[o * 9 + k];
            // 16B unit = ((n*9+k)*8 + cb)*64 + cout; halfword cl
            w_bf[((((n * 9 + k) * 8 + cb) * 64 + cout) << 3) + cl] = f2bf(mod * wv);
        }
    } else {
        float s = bias_b1[tid];
        const float* wrow = bias_w1 + tid * AUXD;
        #pragma unroll 4
        for (int a = 0; a < AUXD; ++a) s += ylds[a] * wrow[a];
        float ap = bias_prelu[0];
        hl[tid] = s >= 0.f ? s : ap * s;
        __syncthreads();
        if (tid < COUT) {
            float t = bias_b2[tid];
            const float* w2row = bias_w2 + tid * HIDD;
            #pragma unroll 4
            for (int h = 0; h < HIDD; ++h) t += hl[h] * w2row[h];
            bvec[n * COUT + tid] = t;
        }
    }
}

// ---------------- Kernel 2: conv ----------------
#define ISSUE(k) { _Pragma("unroll") \
    for (int i = 0; i < 16; ++i) st[i] = xr[k][(size_t)(nci + i) * HWP]; }

#define WRITE(k) { float vm = vmr[k]; \
    unsigned char* dst = nx + (rg + 2 * (k)) * XROW + (sw + 1) * 32; \
    uint4 lo, hi; \
    lo.x = pk2(st[0], st[1], vm);  lo.y = pk2(st[2], st[3], vm); \
    lo.z = pk2(st[4], st[5], vm);  lo.w = pk2(st[6], st[7], vm); \
    hi.x = pk2(st[8], st[9], vm);  hi.y = pk2(st[10], st[11], vm); \
    hi.z = pk2(st[12], st[13], vm); hi.w = pk2(st[14], st[15], vm); \
    *(uint4*)dst = lo; *(uint4*)(dst + 16) = hi; }

__global__ __launch_bounds__(512, 4) void conv_kernel(
    const float* __restrict__ x, const unsigned short* __restrict__ w_bf,
    const float* __restrict__ bvec, float* __restrict__ out)
{
    __shared__ __align__(16) unsigned char smem[SMEMB];

    const int bid = blockIdx.x;
    const int n = bid & 7;              // sample -> XCD (weights + x L2 locality)
    const int h0 = (bid >> 3) * 2;      // first output row

    const int tid = threadIdx.x;
    const int lane = tid & 63;
    const int wave = tid >> 6;
    const int wr = wave >> 2;           // output row 0..1
    const int wq = wave & 3;            // col quarter
    const int l5 = lane >> 5;           // K half
    const int l31 = lane & 31;

    const int sw = tid & 255;           // staging col
    const int rg = tid >> 8;            // 0..1; this thread stages rows rg, rg+2

    // staging row pointers (clamped + zero mask at image edges)
    const float* xr[2];
    float vmr[2];
    #pragma unroll
    for (int k = 0; k < 2; ++k) {
        int r = rg + 2 * k;
        int hin = h0 - 1 + r;
        bool val = (hin >= 0) && (hin < HH);
        xr[k] = x + (size_t)n * CIN * HWP + (size_t)(val ? hin : 0) * WW + sw;
        vmr[k] = val ? 1.f : 0.f;
    }

    const uint4* wsrc = (const uint4*)w_bf + (size_t)n * (9 * 8 * 64);

    // zero halo entries (w-index 0 and 257), 4 rows, both buffers, 2 halves
    if (tid < 32) {
        int buf = tid >> 4, side = (tid >> 3) & 1, r = (tid >> 1) & 3, hf = tid & 1;
        uint4 z; z.x = z.y = z.z = z.w = 0u;
        *(uint4*)(smem + buf * XBUF + r * XROW + (side ? 257 : 0) * 32 + hf * 16) = z;
    }

    // prologue: stage chunk 0 (ci 0..15) into buf 0
    #pragma unroll
    for (int k = 0; k < 2; ++k) {
        float st[16];
        #pragma unroll
        for (int i = 0; i < 16; ++i) st[i] = xr[k][(size_t)i * HWP];
        float vm = vmr[k];
        unsigned char* dst = smem + (rg + 2 * k) * XROW + (sw + 1) * 32;
        uint4 lo, hi;
        lo.x = pk2(st[0], st[1], vm);  lo.y = pk2(st[2], st[3], vm);
        lo.z = pk2(st[4], st[5], vm);  lo.w = pk2(st[6], st[7], vm);
        hi.x = pk2(st[8], st[9], vm);  hi.y = pk2(st[10], st[11], vm);
        hi.z = pk2(st[12], st[13], vm); hi.w = pk2(st[14], st[15], vm);
        *(uint4*)dst = lo; *(uint4*)(dst + 16) = hi;
    }

    // acc init = per-cout bias (D row = (reg&3) + 8*(reg>>2) + 4*l5)
    f32x16 acc[2][2];
    #pragma unroll
    for (int m = 0; m < 2; ++m) {
        #pragma unroll
        for (int reg = 0; reg < 16; ++reg)
            acc[m][0][reg] = bvec[n * COUT + m * 32 + (reg & 3) + 8 * (reg >> 2) + 4 * l5];
        acc[m][1] = acc[m][0];
    }

    __syncthreads();

    for (int c = 0; c < 4; ++c) {
        const int p = c & 1;
        const unsigned char* rbuf = smem + p * XBUF;
        unsigned char* nx = smem + (p ^ 1) * XBUF;
        const bool more = (c < 3);
        const int nci = (c + 1) * 16;

        // A-frags kidx 0: lane holds A[cout = m*32+l31][k = 8*l5 + j]
        bf16x8 aA, aB, nA, nB;
        {
            int u = (c * 2 + l5) * 64 + l31;
            aA = *(const bf16x8*)(wsrc + u);
            aB = *(const bf16x8*)(wsrc + u + 32);
        }

        float st[16];
        if (more) ISSUE(0);   // T14: issue next-chunk loads early

        #pragma unroll
        for (int kidx = 0; kidx < 9; ++kidx) {
            const int kh = kidx / 3, kw = kidx % 3;
            if (kidx < 8) {
                int u = ((kidx + 1) * 8 + c * 2 + l5) * 64 + l31;
                nA = *(const bf16x8*)(wsrc + u);
                nB = *(const bf16x8*)(wsrc + u + 32);
            }
            // B-frags: lane holds B[k = 8*l5+j][col = l31] = x[wr+kh][col+kw]
            const unsigned char* bb = rbuf + (wr + kh) * XROW + l5 * 16;
            bf16x8 b0 = *(const bf16x8*)(bb + (wq * 64 + l31 + kw) * 32);
            bf16x8 b1 = *(const bf16x8*)(bb + (wq * 64 + 32 + l31 + kw) * 32);

            if (more) {
                if (kidx == 3)      { WRITE(0); ISSUE(1); }
                else if (kidx == 7) { WRITE(1); }
            }

            mfma32(acc[0][0], aA, b0);
            mfma32(acc[0][1], aA, b1);
            mfma32(acc[1][0], aB, b0);
            mfma32(acc[1][1], aB, b1);
            aA = nA; aB = nB;
        }
        __syncthreads();
    }

    // epilogue: D col = l31, row = (reg&3) + 8*(reg>>2) + 4*l5
    const int hout = h0 + wr;
    float* ob = out + ((size_t)n * COUT * HH + hout) * WW;
    #pragma unroll
    for (int m = 0; m < 2; ++m) {
        #pragma unroll
        for (int j = 0; j < 2; ++j) {
            int colb = wq * 64 + j * 32 + l31;
            #pragma unroll
            for (int reg = 0; reg < 16; ++reg) {
                int cout = m * 32 + (reg & 3) + 8 * (reg >> 2) + 4 * l5;
                ob[(size_t)cout * HWP + colb] = acc[m][j][reg];
            }
        }
    }
}

extern "C" void kernel_launch(void* const* d_in, const int* in_sizes, int n_in,
                              void* d_out, int out_size, void* d_ws, size_t ws_size,
                              hipStream_t stream) {
    const float* x          = (const float*)d_in[0];
    const float* y          = (const float*)d_in[1];
    const float* weight     = (const float*)d_in[2];
    const float* fc_w1      = (const float*)d_in[3];
    const float* fc_b1      = (const float*)d_in[4];
    const float* fc_prelu   = (const float*)d_in[5];
    const float* fc_w2      = (const float*)d_in[6];
    const float* fc_b2      = (const float*)d_in[7];
    const float* bias_w1    = (const float*)d_in[8];
    const float* bias_b1    = (const float*)d_in[9];
    const float* bias_prelu = (const float*)d_in[10];
    const float* bias_w2    = (const float*)d_in[11];
    const float* bias_b2    = (const float*)d_in[12];
    float* out = (float*)d_out;

    unsigned short* w_bf = (unsigned short*)d_ws;                       // 589824 B
    float* bvec = (float*)((char*)d_ws + (size_t)NB * 9 * 64 * 64 * 2); // 2048 B

    hipLaunchKernelGGL(mlp_kernel, dim3(17, 8), dim3(256), 0, stream,
                       y, weight, fc_w1, fc_b1, fc_prelu, fc_w2, fc_b2,
                       bias_w1, bias_b1, bias_prelu, bias_w2, bias_b2, w_bf, bvec);
    hipLaunchKernelGGL(conv_kernel, dim3(1024), dim3(512), 0, stream,
                       x, w_bf, bvec, out);
}

// Round 5
// 87.652 us; speedup vs baseline: 1.3964x; 1.3712x over previous
//
#include <hip/hip_runtime.h>
#include <hip/hip_bf16.h>

// ModConv2d: per-sample modulated 3x3 conv (N=8, C=64->64, 256x256) + MLPs.
// Kernel 1: MLPs -> w_bf[n][kidx][cb][cout][8ci] (bf16, A-frag 16B units) + bias.
// Kernel 2: implicit-GEMM conv, builtin mfma_f32_32x32x16_bf16 (acc in AGPR natively).
//   Block: 512 thr (8 waves), 2 output rows x 256 cols x 64 couts. Grid 1024.
//   ALL weights in LDS (73.7 KB, staged once) -> chunk body has no global loads
//   except x staging -> compiler pipelines ds_reads (m97 shape).
//   x LDS: [4 rows][2 ci-half][258][16B], dbuf 66 KB; staging writes contiguous
//   1024B/wave (conflict-free). Total LDS 139.8 KB, 1 block/CU, 2 waves/SIMD.
//   One barrier per 16-ci chunk; T14 issue-early/write-late staging split.

typedef short bf16x8 __attribute__((ext_vector_type(8)));
typedef float f32x16 __attribute__((ext_vector_type(16)));

#define NB 8
#define CIN 64
#define COUT 64
#define HH 256
#define WW 256
#define HWP (HH * WW)
#define AUXD 128
#define HIDD 256

#define XH 4128             // half-ci plane: 258 * 16B
#define XRW (2 * XH)        // staged row: 2 halves = 8256 B
#define XBUF (4 * XRW)      // 4 rows = 33024 B
#define WOFF (2 * XBUF)     // 66048
#define WBYTES (9 * 8 * 64 * 16)  // 73728
#define SMEMB (WOFF + WBYTES)     // 139776

__device__ __forceinline__ unsigned short f2bf(float f) {
    unsigned u = __builtin_bit_cast(unsigned, f);
    u += 0x7FFFu + ((u >> 16) & 1u);   // RNE
    return (unsigned short)(u >> 16);
}

__device__ __forceinline__ unsigned pk2(float a, float b, float vm) {
    return (unsigned)f2bf(a * vm) | ((unsigned)f2bf(b * vm) << 16);
}

// ---------------- Kernel 1: MLPs ----------------
__global__ __launch_bounds__(256) void mlp_kernel(
    const float* __restrict__ y, const float* __restrict__ weight,
    const float* __restrict__ fc_w1, const float* __restrict__ fc_b1,
    const float* __restrict__ fc_prelu,
    const float* __restrict__ fc_w2, const float* __restrict__ fc_b2,
    const float* __restrict__ bias_w1, const float* __restrict__ bias_b1,
    const float* __restrict__ bias_prelu,
    const float* __restrict__ bias_w2, const float* __restrict__ bias_b2,
    unsigned short* __restrict__ w_bf, float* __restrict__ bvec)
{
    const int n = blockIdx.y;
    const int c = blockIdx.x;
    const int tid = threadIdx.x;
    __shared__ float ylds[AUXD];
    __shared__ float hl[HIDD];
    if (tid < AUXD) ylds[tid] = y[n * AUXD + tid];
    __syncthreads();

    if (c < 16) {
        float s = fc_b1[tid];
        const float* wrow = fc_w1 + tid * AUXD;
        #pragma unroll 4
        for (int a = 0; a < AUXD; ++a) s += ylds[a] * wrow[a];
        float ap = fc_prelu[0];
        hl[tid] = s >= 0.f ? s : ap * s;
        __syncthreads();

        int o = c * 256 + tid;           // o = cout*64 + ci
        float t = fc_b2[o];
        const float* w2row = fc_w2 + o * HIDD;
        #pragma unroll 4
        for (int h = 0; h < HIDD; ++h) t += hl[h] * w2row[h];
        float mod = 1.f / (1.f + expf(-t));
        int cout = o >> 6, ci = o & 63;
        int cb = ci >> 3, cl = ci & 7;
        #pragma unroll
        for (int k = 0; k < 9; ++k) {
            float wv = weight[o * 9 + k];
            // 16B unit = ((n*9+k)*8 + cb)*64 + cout; halfword cl
            w_bf[((((n * 9 + k) * 8 + cb) * 64 + cout) << 3) + cl] = f2bf(mod * wv);
        }
    } else {
        float s = bias_b1[tid];
        const float* wrow = bias_w1 + tid * AUXD;
        #pragma unroll 4
        for (int a = 0; a < AUXD; ++a) s += ylds[a] * wrow[a];
        float ap = bias_prelu[0];
        hl[tid] = s >= 0.f ? s : ap * s;
        __syncthreads();
        if (tid < COUT) {
            float t = bias_b2[tid];
            const float* w2row = bias_w2 + tid * HIDD;
            #pragma unroll 4
            for (int h = 0; h < HIDD; ++h) t += hl[h] * w2row[h];
            bvec[n * COUT + tid] = t;
        }
    }
}

// ---------------- Kernel 2: conv ----------------
#define ISSUE(k) { _Pragma("unroll") \
    for (int i = 0; i < 16; ++i) st[i] = xr[k][(size_t)(nci + i) * HWP]; }

#define WRITE(k) { float vm = vmr[k]; \
    unsigned char* dst = nx + (rg + 2 * (k)) * XRW + (sw + 1) * 16; \
    uint4 lo, hi; \
    lo.x = pk2(st[0], st[1], vm);  lo.y = pk2(st[2], st[3], vm); \
    lo.z = pk2(st[4], st[5], vm);  lo.w = pk2(st[6], st[7], vm); \
    hi.x = pk2(st[8], st[9], vm);  hi.y = pk2(st[10], st[11], vm); \
    hi.z = pk2(st[12], st[13], vm); hi.w = pk2(st[14], st[15], vm); \
    *(uint4*)dst = lo; *(uint4*)(dst + XH) = hi; }

__global__ __launch_bounds__(512, 2) void conv_kernel(
    const float* __restrict__ x, const unsigned short* __restrict__ w_bf,
    const float* __restrict__ bvec, float* __restrict__ out)
{
    __shared__ __align__(16) unsigned char smem[SMEMB];

    const int bid = blockIdx.x;
    const int n = bid & 7;              // sample -> XCD (x L2/L3 locality)
    const int h0 = (bid >> 3) * 2;      // first output row

    const int tid = threadIdx.x;
    const int lane = tid & 63;
    const int wave = tid >> 6;
    const int wr = wave >> 2;           // output row 0..1
    const int wq = wave & 3;            // col quarter
    const int l5 = lane >> 5;           // K half
    const int l31 = lane & 31;

    const int sw = tid & 255;           // staging col
    const int rg = tid >> 8;            // 0..1; this thread stages rows rg, rg+2

    // staging row pointers (clamped + zero mask at image edges)
    const float* xr[2];
    float vmr[2];
    #pragma unroll
    for (int k = 0; k < 2; ++k) {
        int r = rg + 2 * k;
        int hin = h0 - 1 + r;
        bool val = (hin >= 0) && (hin < HH);
        xr[k] = x + (size_t)n * CIN * HWP + (size_t)(val ? hin : 0) * WW + sw;
        vmr[k] = val ? 1.f : 0.f;
    }

    // ---- stage ALL weights for this sample into LDS (A-frag linear layout) ----
    {
        const uint4* wsrc = (const uint4*)w_bf + (size_t)n * (9 * 8 * 64);
        #pragma unroll
        for (int it = 0; it < 9; ++it) {
            int idx = it * 512 + tid;
            uint4 v = wsrc[idx];
            *(uint4*)(smem + WOFF + (idx << 4)) = v;
        }
    }

    // zero halo entries (w-index 0 and 257): 4 rows x 2 halves x 2 sides x 2 bufs
    if (tid < 32) {
        int buf = tid >> 4, side = (tid >> 3) & 1, r = (tid >> 1) & 3, hf = tid & 1;
        uint4 z; z.x = z.y = z.z = z.w = 0u;
        *(uint4*)(smem + buf * XBUF + r * XRW + hf * XH + (side ? 257 : 0) * 16) = z;
    }

    // prologue: stage chunk 0 (ci 0..15) into buf 0
    #pragma unroll
    for (int k = 0; k < 2; ++k) {
        float st[16];
        #pragma unroll
        for (int i = 0; i < 16; ++i) st[i] = xr[k][(size_t)i * HWP];
        float vm = vmr[k];
        unsigned char* dst = smem + (rg + 2 * k) * XRW + (sw + 1) * 16;
        uint4 lo, hi;
        lo.x = pk2(st[0], st[1], vm);  lo.y = pk2(st[2], st[3], vm);
        lo.z = pk2(st[4], st[5], vm);  lo.w = pk2(st[6], st[7], vm);
        hi.x = pk2(st[8], st[9], vm);  hi.y = pk2(st[10], st[11], vm);
        hi.z = pk2(st[12], st[13], vm); hi.w = pk2(st[14], st[15], vm);
        *(uint4*)dst = lo; *(uint4*)(dst + XH) = hi;
    }

    // acc init = per-cout bias (D row = (reg&3) + 8*(reg>>2) + 4*l5)
    f32x16 acc[2][2];
    #pragma unroll
    for (int m = 0; m < 2; ++m) {
        #pragma unroll
        for (int reg = 0; reg < 16; ++reg)
            acc[m][0][reg] = bvec[n * COUT + m * 32 + (reg & 3) + 8 * (reg >> 2) + 4 * l5];
        acc[m][1] = acc[m][0];
    }

    __syncthreads();

    for (int c = 0; c < 4; ++c) {
        const int p = c & 1;
        const unsigned char* rbuf = smem + p * XBUF;
        unsigned char* nx = smem + (p ^ 1) * XBUF;
        const bool more = (c < 3);
        const int nci = (c + 1) * 16;

        float st[16];
        if (more) ISSUE(0);   // T14: issue next-chunk loads early

        #pragma unroll
        for (int kidx = 0; kidx < 9; ++kidx) {
            const int kh = kidx / 3, kw = kidx % 3;
            // A-frags from LDS: lane holds A[cout = m*32+l31][k = 8*l5 + j]
            const unsigned char* ab = smem + WOFF +
                (((kidx * 8 + c * 2 + l5) * 64 + l31) << 4);
            bf16x8 aA = *(const bf16x8*)ab;
            bf16x8 aB = *(const bf16x8*)(ab + 512);
            // B-frags: lane holds B[k = 8*l5+j][col = l31] = x[wr+kh][col+kw]
            const unsigned char* bb = rbuf + (wr + kh) * XRW + l5 * XH;
            bf16x8 b0 = *(const bf16x8*)(bb + (wq * 64 + l31 + kw) * 16);
            bf16x8 b1 = *(const bf16x8*)(bb + (wq * 64 + 32 + l31 + kw) * 16);

            if (more) {
                if (kidx == 3)      { WRITE(0); ISSUE(1); }
                else if (kidx == 7) { WRITE(1); }
            }

            acc[0][0] = __builtin_amdgcn_mfma_f32_32x32x16_bf16(aA, b0, acc[0][0], 0, 0, 0);
            acc[0][1] = __builtin_amdgcn_mfma_f32_32x32x16_bf16(aA, b1, acc[0][1], 0, 0, 0);
            acc[1][0] = __builtin_amdgcn_mfma_f32_32x32x16_bf16(aB, b0, acc[1][0], 0, 0, 0);
            acc[1][1] = __builtin_amdgcn_mfma_f32_32x32x16_bf16(aB, b1, acc[1][1], 0, 0, 0);
        }
        __syncthreads();
    }

    // epilogue: D col = l31, row = (reg&3) + 8*(reg>>2) + 4*l5
    const int hout = h0 + wr;
    float* ob = out + ((size_t)n * COUT * HH + hout) * WW;
    #pragma unroll
    for (int m = 0; m < 2; ++m) {
        #pragma unroll
        for (int j = 0; j < 2; ++j) {
            int colb = wq * 64 + j * 32 + l31;
            #pragma unroll
            for (int reg = 0; reg < 16; ++reg) {
                int cout = m * 32 + (reg & 3) + 8 * (reg >> 2) + 4 * l5;
                ob[(size_t)cout * HWP + colb] = acc[m][j][reg];
            }
        }
    }
}

extern "C" void kernel_launch(void* const* d_in, const int* in_sizes, int n_in,
                              void* d_out, int out_size, void* d_ws, size_t ws_size,
                              hipStream_t stream) {
    const float* x          = (const float*)d_in[0];
    const float* y          = (const float*)d_in[1];
    const float* weight     = (const float*)d_in[2];
    const float* fc_w1      = (const float*)d_in[3];
    const float* fc_b1      = (const float*)d_in[4];
    const float* fc_prelu   = (const float*)d_in[5];
    const float* fc_w2      = (const float*)d_in[6];
    const float* fc_b2      = (const float*)d_in[7];
    const float* bias_w1    = (const float*)d_in[8];
    const float* bias_b1    = (const float*)d_in[9];
    const float* bias_prelu = (const float*)d_in[10];
    const float* bias_w2    = (const float*)d_in[11];
    const float* bias_b2    = (const float*)d_in[12];
    float* out = (float*)d_out;

    unsigned short* w_bf = (unsigned short*)d_ws;                       // 589824 B
    float* bvec = (float*)((char*)d_ws + (size_t)NB * 9 * 64 * 64 * 2); // 2048 B

    hipLaunchKernelGGL(mlp_kernel, dim3(17, 8), dim3(256), 0, stream,
                       y, weight, fc_w1, fc_b1, fc_prelu, fc_w2, fc_b2,
                       bias_w1, bias_b1, bias_prelu, bias_w2, bias_b2, w_bf, bvec);
    hipLaunchKernelGGL(conv_kernel, dim3(1024), dim3(512), 0, stream,
                       x, w_bf, bvec, out);
}